// Round 6
// baseline (446.022 us; speedup 1.0000x reference)
//
#include <hip/hip_runtime.h>
#include <math.h>

typedef __attribute__((ext_vector_type(8))) short   short8;
typedef __attribute__((ext_vector_type(4))) short   short4v;
typedef __attribute__((ext_vector_type(8))) __bf16  bf16x8;
typedef __attribute__((ext_vector_type(4))) float   f32x4;
typedef unsigned short u16;

#define DIMD 1024
#define NHEAD 16
#define HD 64
#define FFD 4096
#define BB 2
#define SSEQ 2048
#define NSPLIT 4
#define KVSPAN (SSEQ / NSPLIT)
#define NROWS (BB * NHEAD * SSEQ)
#define NEGF -3.4028235e38f

__device__ __forceinline__ u16 f2bf(float f){
  unsigned u = __float_as_uint(f);
  u += 0x7FFFu + ((u >> 16) & 1u);
  return (u16)(u >> 16);
}
__device__ __forceinline__ float bf2f(u16 v){
  return __uint_as_float(((unsigned)v) << 16);
}
__device__ __forceinline__ void gload16(const u16* g, u16* l){
  __builtin_amdgcn_global_load_lds((const __attribute__((address_space(1))) void*)g,
                                   (__attribute__((address_space(3))) void*)l, 16, 0, 0);
}

// ---------------- mask dtype discriminator + normalizer ----------------
__global__ void normalize_mask(const unsigned char* __restrict__ m, unsigned char* __restrict__ outm){
  __shared__ int any;
  if (threadIdx.x == 0) any = 0;
  __syncthreads();
  int bad = 0;
  for (int i = threadIdx.x; i < BB * SSEQ; i += 1024)
    if ((i & 3) && m[i]) bad = 1;
  if (bad) atomicOr(&any, 1);
  __syncthreads();
  bool is_i32 = (any == 0);
  if (is_i32){
    const int* mi = (const int*)m;
    for (int k = threadIdx.x; k < BB * SSEQ; k += 1024)
      outm[k] = (unsigned char)(mi[k] != 0);
  } else {
    for (int k = threadIdx.x; k < BB * SSEQ; k += 1024)
      outm[k] = m[k] ? 1 : 0;
  }
}

// ---------------- weight transpose + fp32->bf16 ----------------
__global__ void transpose_to_bf16(const float* __restrict__ W, u16* __restrict__ Wt, int K, int N){
  __shared__ float tile[32][33];
  int n0 = blockIdx.x * 32, k0 = blockIdx.y * 32;
  int tx = threadIdx.x, ty = threadIdx.y;   // 32 x 8
  #pragma unroll
  for (int i = 0; i < 32; i += 8)
    tile[ty + i][tx] = W[(size_t)(k0 + ty + i) * N + n0 + tx];
  __syncthreads();
  #pragma unroll
  for (int i = 0; i < 32; i += 8)
    Wt[(size_t)(n0 + ty + i) * K + k0 + tx] = f2bf(tile[tx][ty + i]);
}

// ---------------- RMSNorm: fp32 in -> bf16 out ----------------
__global__ __launch_bounds__(256) void rmsnorm_k(const float* __restrict__ x, const float* __restrict__ g,
                                                 u16* __restrict__ out, int D){
  int row = blockIdx.x;
  const float* xr = x + (size_t)row * D;
  float ss = 0.f;
  for (int i = threadIdx.x * 4; i < D; i += 1024){
    float4 v = *(const float4*)&xr[i];
    ss += v.x*v.x + v.y*v.y + v.z*v.z + v.w*v.w;
  }
  #pragma unroll
  for (int o = 32; o > 0; o >>= 1) ss += __shfl_down(ss, o);
  __shared__ float red[4];
  if ((threadIdx.x & 63) == 0) red[threadIdx.x >> 6] = ss;
  __syncthreads();
  float tot = red[0] + red[1] + red[2] + red[3];
  float rs = rsqrtf(tot / (float)D + 1e-6f);
  for (int i = threadIdx.x * 4; i < D; i += 1024){
    float4 v  = *(const float4*)&xr[i];
    float4 gv = *(const float4*)&g[i];
    ushort4 o4;
    o4.x = f2bf(v.x * rs * gv.x);
    o4.y = f2bf(v.y * rs * gv.y);
    o4.z = f2bf(v.z * rs * gv.z);
    o4.w = f2bf(v.w * rs * gv.w);
    *(ushort4*)&out[(size_t)row * D + i] = o4;
  }
}

// ================= 8-phase-style 256x256 GEMM, BK=32, 3-deep pipeline =================
template<int EPI>
__global__ __launch_bounds__(512, 2) void gemm8p(const u16* __restrict__ A, const u16* __restrict__ Bt,
                                                 u16* __restrict__ outb, const float* __restrict__ bias,
                                                 int M, int N, int K){
  extern __shared__ u16 lds[];   // 3 * 16384 u16
  const int tid = threadIdx.x;
  const int lane = tid & 63, lr = lane >> 4, lc = lane & 15;
  const int wid = tid >> 6, wr = wid >> 2, wc = wid & 3;
  const int m0 = blockIdx.y * 256, n0 = blockIdx.x * 256;
  const int NT = K >> 5;
  const int slot8 = ((lr ^ (lc & 3)) << 3);   // swizzled k-slot (u16 units)

  f32x4 acc[8][4];
  #pragma unroll
  for (int i = 0; i < 8; i++)
    #pragma unroll
    for (int j = 0; j < 4; j++) acc[i][j] = (f32x4){0.f,0.f,0.f,0.f};

  const int srow = tid >> 2;
  const int scg  = (tid & 3) ^ (srow & 3);

  auto stage = [&](int t, int buf, int rsel){
    int row = ((rsel & 1) << 7) + srow;
    const u16* src = ((rsel < 2) ? A + (size_t)(m0 + row) * K
                                 : Bt + (size_t)(n0 + row) * K) + t * 32 + scg * 8;
    u16* dst = lds + buf * 16384 + ((rsel & 2) << 12) + ((rsel & 1) << 12) + tid * 8;
    gload16(src, dst);
  };
  auto ldA = [&](int buf, int mi) -> bf16x8 {
    int ra = wr * 128 + mi * 16 + lc;
    return *(const bf16x8*)&lds[buf * 16384 + ra * 32 + slot8];
  };
  auto ldB = [&](int buf, int ni) -> bf16x8 {
    int rb = wc * 64 + ni * 16 + lc;
    return *(const bf16x8*)&lds[buf * 16384 + 8192 + rb * 32 + slot8];
  };

  #pragma unroll
  for (int rs = 0; rs < 4; rs++) stage(0, 0, rs);
  #pragma unroll
  for (int rs = 0; rs < 4; rs++) stage(1, 1, rs);
  asm volatile("s_waitcnt vmcnt(4)" ::: "memory");
  __builtin_amdgcn_s_barrier();

  int buf = 0;
  for (int t = 0; t < NT; t++){
    int sbuf = buf + 2; if (sbuf >= 3) sbuf -= 3;
    bool ds = (t + 2 < NT);
    bf16x8 a[4], b[4];
    #pragma unroll
    for (int mi = 0; mi < 4; mi++) a[mi] = ldA(buf, mi);
    #pragma unroll
    for (int ni = 0; ni < 4; ni++) b[ni] = ldB(buf, ni);
    if (ds){ stage(t + 2, sbuf, 0); stage(t + 2, sbuf, 1); }
    __builtin_amdgcn_s_barrier();
    __builtin_amdgcn_s_setprio(1);
    #pragma unroll
    for (int mi = 0; mi < 4; mi++)
      #pragma unroll
      for (int ni = 0; ni < 4; ni++)
        acc[mi][ni] = __builtin_amdgcn_mfma_f32_16x16x32_bf16(a[mi], b[ni], acc[mi][ni], 0, 0, 0);
    __builtin_amdgcn_s_setprio(0);
    __builtin_amdgcn_s_barrier();
    #pragma unroll
    for (int mi = 0; mi < 4; mi++) a[mi] = ldA(buf, mi + 4);
    if (ds){ stage(t + 2, sbuf, 2); stage(t + 2, sbuf, 3); }
    __builtin_amdgcn_s_barrier();
    __builtin_amdgcn_s_setprio(1);
    #pragma unroll
    for (int mi = 0; mi < 4; mi++)
      #pragma unroll
      for (int ni = 0; ni < 4; ni++)
        acc[mi + 4][ni] = __builtin_amdgcn_mfma_f32_16x16x32_bf16(a[mi], b[ni], acc[mi + 4][ni], 0, 0, 0);
    __builtin_amdgcn_s_setprio(0);
    if (t + 2 < NT)      { asm volatile("s_waitcnt vmcnt(4)" ::: "memory"); }
    else if (t + 1 < NT) { asm volatile("s_waitcnt vmcnt(0)" ::: "memory"); }
    __builtin_amdgcn_s_barrier();
    buf++; if (buf == 3) buf = 0;
  }

  #pragma unroll
  for (int mi = 0; mi < 8; mi++){
    #pragma unroll
    for (int ni = 0; ni < 4; ni++){
      int col = n0 + wc * 64 + ni * 16 + lc;
      #pragma unroll
      for (int r = 0; r < 4; r++){
        int row = m0 + wr * 128 + mi * 16 + lr * 4 + r;
        float v = acc[mi][ni][r];
        if (EPI == 2){
          v += bias[col];
          v = 0.5f * v * (1.f + erff(v * 0.70710678118654752f));
        }
        outb[(size_t)row * N + col] = f2bf(v);
      }
    }
  }
}

// ---------------- GEMM (m97 structure): O-proj / FFN2 ----------------
template<int EPI, int BN>
__global__ __launch_bounds__(256) void gemm_bt(const u16* __restrict__ A, const u16* __restrict__ Bt,
                                               u16* __restrict__ outb, float* __restrict__ outf,
                                               const float* __restrict__ bias, const float* __restrict__ resid,
                                               int M, int N, int K){
  constexpr int NI = BN / 32;
  __shared__ u16 As[128 * 64];
  __shared__ u16 Bs[BN * 64];
  const int tid = threadIdx.x;
  const int wid = tid >> 6, lane = tid & 63, lr = lane >> 4, lc = lane & 15;
  const int wr = wid >> 1, wc = wid & 1;
  const int m0 = blockIdx.y * 128, n0 = blockIdx.x * BN;

  f32x4 acc[4][NI];
  #pragma unroll
  for (int i = 0; i < 4; i++)
    #pragma unroll
    for (int j = 0; j < NI; j++) acc[i][j] = (f32x4){0.f,0.f,0.f,0.f};

  for (int k0 = 0; k0 < K; k0 += 64){
    __syncthreads();
    #pragma unroll
    for (int j = 0; j < 4; j++){
      int c = tid + 256 * j;
      gload16(A + (size_t)(m0 + (c >> 3)) * K + k0 + (c & 7) * 8, As + c * 8);
    }
    #pragma unroll
    for (int j = 0; j < NI; j++){
      int c = tid + 256 * j;
      gload16(Bt + (size_t)(n0 + (c >> 3)) * K + k0 + (c & 7) * 8, Bs + c * 8);
    }
    __syncthreads();
    #pragma unroll
    for (int kk = 0; kk < 2; kk++){
      bf16x8 a[4], b[NI];
      #pragma unroll
      for (int mi = 0; mi < 4; mi++) a[mi] = *(const bf16x8*)&As[(wr*64 + mi*16 + lc)*64 + kk*32 + lr*8];
      #pragma unroll
      for (int ni = 0; ni < NI; ni++) b[ni] = *(const bf16x8*)&Bs[(wc*(BN/2) + ni*16 + lc)*64 + kk*32 + lr*8];
      #pragma unroll
      for (int mi = 0; mi < 4; mi++)
        #pragma unroll
        for (int ni = 0; ni < NI; ni++)
          acc[mi][ni] = __builtin_amdgcn_mfma_f32_16x16x32_bf16(a[mi], b[ni], acc[mi][ni], 0, 0, 0);
    }
  }

  #pragma unroll
  for (int mi = 0; mi < 4; mi++){
    #pragma unroll
    for (int ni = 0; ni < NI; ni++){
      #pragma unroll
      for (int r = 0; r < 4; r++){
        int row = m0 + wr*64 + mi*16 + lr*4 + r;
        int col = n0 + wc*(BN/2) + ni*16 + lc;
        float v = acc[mi][ni][r];
        size_t idx = (size_t)row * N + col;
        if (EPI == 0){
          outb[idx] = f2bf(v);
        } else if (EPI == 1){
          outf[idx] = v + resid[idx];
        } else if (EPI == 2){
          v += bias[col];
          v = 0.5f * v * (1.f + erff(v * 0.70710678118654752f));
          outb[idx] = f2bf(v);
        } else {
          outf[idx] = v + bias[col] + resid[idx];
        }
      }
    }
  }
}

// ---------------- flash attention, split-KV partial (swapped QK^T) ----------------
__device__ __forceinline__ void vts_store(char* vts, int row, int col, u16 val){
  int byte = (row * 72 + col) * 2;
  byte ^= ((row >> 3) & 7) << 4;
  *(u16*)(vts + byte) = val;
}
__device__ __forceinline__ bf16x8 vts_load(const char* vts, int row, int colbase){
  int byte = (row * 72 + colbase) * 2;
  byte ^= ((row >> 3) & 7) << 4;
  return *(const bf16x8*)(vts + byte);
}

// grid (2*S/64, H, NSPLIT): blockIdx.x = qblk*2 + b
__global__ __launch_bounds__(256) void attn_part(const u16* __restrict__ qkv, const float* __restrict__ bias,
                                                 const unsigned char* __restrict__ mask,
                                                 u16* __restrict__ Opart, float* __restrict__ mp, float* __restrict__ lp){
  __shared__ u16 Ks [64][72];
  __shared__ u16 VtsB[64 * 72];
  __shared__ u16 PsB [4 * 16 * 72];

  const int tid = threadIdx.x;
  const int wid = tid >> 6, lane = tid & 63, lr = lane >> 4, lc = lane & 15;
  const int b  = blockIdx.x & 1;
  const int q0 = (blockIdx.x >> 1) * 64;
  const int h  = blockIdx.y;
  const int sp = blockIdx.z;
  const int qrow = q0 + wid * 16;
  const int kv_lo = sp * KVSPAN, kv_hi = kv_lo + KVSPAN;

  char* vts = (char*)VtsB;
  u16*  psw = PsB + wid * 16 * 72;

  bf16x8 qf0, qf1;
  {
    const u16* qp = qkv + ((size_t)(b * SSEQ + qrow + lc)) * 3072 + h * HD;
    qf0 = *(const bf16x8*)(qp + lr * 8);
    qf1 = *(const bf16x8*)(qp + 32 + lr * 8);
  }

  const int c0 = tid, c1 = tid + 256;
  const u16* kvbase = qkv + (size_t)b * SSEQ * 3072 + 1024 + h * HD;
  auto kaddr = [&](int kv0, int c){ return kvbase + (size_t)(kv0 + (c >> 3)) * 3072 + (c & 7) * 8; };

  // bias/mask vector loads for a tile: per lane q=lc row, keys ni*16+lr*4..+3
  const float* brow = bias + ((size_t)h * SSEQ + (qrow + lc)) * SSEQ;
  const unsigned char* mrow_p = mask + b * SSEQ;
  float4 bvA[4]; unsigned mkA[4];
  auto bload = [&](int kv0, float4* bv, unsigned* mk){
    #pragma unroll
    for (int ni = 0; ni < 4; ni++){
      int key = kv0 + ni * 16 + lr * 4;
      bv[ni] = *(const float4*)&brow[key];
      mk[ni] = *(const unsigned*)&mrow_p[key];
    }
  };

  // prologue: first tile K/V + bias/mask
  short8 kr0 = *(const short8*)kaddr(kv_lo, c0);
  short8 vr0 = *(const short8*)(kaddr(kv_lo, c0) + 1024);
  short8 kr1 = *(const short8*)kaddr(kv_lo, c1);
  short8 vr1 = *(const short8*)(kaddr(kv_lo, c1) + 1024);
  bload(kv_lo, bvA, mkA);

  float mrow = NEGF, lsum = 0.f;   // per lane: q = qrow + lc (4 copies across lr)
  f32x4 oacc[4];
  #pragma unroll
  for (int d = 0; d < 4; d++) oacc[d] = (f32x4){0.f,0.f,0.f,0.f};

  for (int kv0 = kv_lo; kv0 < kv_hi; kv0 += 64){
    __syncthreads();
    *(short8*)&Ks[c0 >> 3][(c0 & 7) * 8] = kr0;
    *(short8*)&Ks[c1 >> 3][(c1 & 7) * 8] = kr1;
    #pragma unroll
    for (int j = 0; j < 8; j++){
      vts_store(vts, (c0 & 7) * 8 + j, c0 >> 3, (u16)vr0[j]);
      vts_store(vts, (c1 & 7) * 8 + j, c1 >> 3, (u16)vr1[j]);
    }
    __syncthreads();

    // prefetch next tile: K/V + bias/mask (latency hides under compute below)
    int nxt = (kv0 + 64 < kv_hi) ? kv0 + 64 : kv_lo;
    kr0 = *(const short8*)kaddr(nxt, c0);
    vr0 = *(const short8*)(kaddr(nxt, c0) + 1024);
    kr1 = *(const short8*)kaddr(nxt, c1);
    vr1 = *(const short8*)(kaddr(nxt, c1) + 1024);
    float4 bvB[4]; unsigned mkB[4];
    bload(nxt, bvB, mkB);

    // ---- QK^T swapped: sf[ni][r] = S[key = kv0+ni*16+lr*4+r][q = qrow+lc] ----
    f32x4 sf[4];
    #pragma unroll
    for (int ni = 0; ni < 4; ni++) sf[ni] = (f32x4){0.f,0.f,0.f,0.f};
    __builtin_amdgcn_s_setprio(1);
    #pragma unroll
    for (int ni = 0; ni < 4; ni++){
      bf16x8 kf0 = *(const bf16x8*)&Ks[ni*16 + lc][lr*8];
      bf16x8 kf1 = *(const bf16x8*)&Ks[ni*16 + lc][32 + lr*8];
      sf[ni] = __builtin_amdgcn_mfma_f32_16x16x32_bf16(kf0, qf0, sf[ni], 0, 0, 0);
      sf[ni] = __builtin_amdgcn_mfma_f32_16x16x32_bf16(kf1, qf1, sf[ni], 0, 0, 0);
    }
    __builtin_amdgcn_s_setprio(0);

    // ---- scores + in-register row max ----
    float s[4][4];
    float tm = NEGF;
    #pragma unroll
    for (int ni = 0; ni < 4; ni++){
      #pragma unroll
      for (int r = 0; r < 4; r++){
        bool mk = ((mkA[ni] >> (8 * r)) & 0xffu) != 0;
        float v = sf[ni][r] * 0.125f + ((const float*)&bvA[ni])[r];
        v = mk ? NEGF : v;
        s[ni][r] = v;
        tm = fmaxf(tm, v);
      }
    }
    tm = fmaxf(tm, __shfl_xor(tm, 16));
    tm = fmaxf(tm, __shfl_xor(tm, 32));

    // ---- defer-max rescale ----
    if (__any(tm > mrow + 5.f)){
      float mnew = fmaxf(mrow, tm);
      float corr = __expf(mrow - mnew);
      lsum *= corr;
      mrow = mnew;
      float cr[4];
      #pragma unroll
      for (int r = 0; r < 4; r++) cr[r] = __shfl(corr, lr * 4 + r);
      #pragma unroll
      for (int d = 0; d < 4; d++)
        #pragma unroll
        for (int r = 0; r < 4; r++) oacc[d][r] *= cr[r];
    }

    // ---- P = exp(s-m), packed b64 store, in-register sum ----
    float psum = 0.f;
    #pragma unroll
    for (int ni = 0; ni < 4; ni++){
      short4v pk;
      #pragma unroll
      for (int r = 0; r < 4; r++){
        float sv = s[ni][r];
        float p = (sv < -1e30f) ? 0.f : __expf(sv - mrow);
        psum += p;
        pk[r] = (short)(__float_as_uint(p) >> 16);
      }
      *(short4v*)&psw[lc * 72 + ni * 16 + lr * 4] = pk;
    }
    psum += __shfl_xor(psum, 16);
    psum += __shfl_xor(psum, 32);
    lsum += psum;

    // ---- PV ----
    __builtin_amdgcn_s_setprio(1);
    #pragma unroll
    for (int kk = 0; kk < 2; kk++){
      bf16x8 pf = *(const bf16x8*)&psw[lc * 72 + kk * 32 + lr * 8];
      #pragma unroll
      for (int d = 0; d < 4; d++){
        bf16x8 vf = vts_load(vts, d*16 + lc, kk*32 + lr*8);
        oacc[d] = __builtin_amdgcn_mfma_f32_16x16x32_bf16(pf, vf, oacc[d], 0, 0, 0);
      }
    }
    __builtin_amdgcn_s_setprio(0);

    #pragma unroll
    for (int ni = 0; ni < 4; ni++){ bvA[ni] = bvB[ni]; mkA[ni] = mkB[ni]; }
  }

  // epilogue: m/l live at lanes lr==0 (q=lc); oacc rows need per-r broadcast
  if (lane < 16){
    int ridx0 = (b * NHEAD + h) * SSEQ + qrow + lc;
    mp[sp * NROWS + ridx0] = mrow;
    lp[sp * NROWS + ridx0] = lsum;
  }
  #pragma unroll
  for (int r = 0; r < 4; r++){
    int ridx = (b * NHEAD + h) * SSEQ + qrow + lr*4 + r;
    #pragma unroll
    for (int d = 0; d < 4; d++)
      Opart[((size_t)(sp * NROWS + ridx)) * HD + d*16 + lc] = f2bf(oacc[d][r]);
  }
}

// ---------------- split-KV merge ----------------
__global__ __launch_bounds__(256) void attn_merge(const u16* __restrict__ Opart, const float* __restrict__ mp,
                                                  const float* __restrict__ lp, u16* __restrict__ attn){
  int row = blockIdx.x * 16 + (threadIdx.x >> 4);
  int tx = threadIdx.x & 15;
  float ms[NSPLIT], ls[NSPLIT];
  float m = NEGF;
  #pragma unroll
  for (int sp = 0; sp < NSPLIT; sp++){
    ms[sp] = mp[sp * NROWS + row];
    ls[sp] = lp[sp * NROWS + row];
    if (ls[sp] > 0.f) m = fmaxf(m, ms[sp]);
  }
  float acc0 = 0.f, acc1 = 0.f, acc2 = 0.f, acc3 = 0.f, ltot = 0.f;
  #pragma unroll
  for (int sp = 0; sp < NSPLIT; sp++){
    float e = (ls[sp] > 0.f) ? __expf(ms[sp] - m) : 0.f;
    ltot += ls[sp] * e;
    ushort4 o4 = *(const ushort4*)&Opart[((size_t)(sp * NROWS + row)) * HD + tx*4];
    acc0 += e * bf2f(o4.x);
    acc1 += e * bf2f(o4.y);
    acc2 += e * bf2f(o4.z);
    acc3 += e * bf2f(o4.w);
  }
  float inv = ltot > 0.f ? 1.f / ltot : 0.f;
  int b = row >> 15, h = (row >> 11) & 15, q = row & 2047;
  ushort4 r4;
  r4.x = f2bf(acc0 * inv);
  r4.y = f2bf(acc1 * inv);
  r4.z = f2bf(acc2 * inv);
  r4.w = f2bf(acc3 * inv);
  *(ushort4*)&attn[((size_t)(b * SSEQ + q)) * DIMD + h * HD + tx*4] = r4;
}

// ---------------- launch ----------------
extern "C" void kernel_launch(void* const* d_in, const int* in_sizes, int n_in,
                              void* d_out, int out_size, void* d_ws, size_t ws_size,
                              hipStream_t stream){
  const float* x    = (const float*)d_in[0];
  const unsigned char* mask = (const unsigned char*)d_in[1];
  const float* bias = (const float*)d_in[2];
  const float* Wq   = (const float*)d_in[3];
  const float* Wk   = (const float*)d_in[4];
  const float* Wv   = (const float*)d_in[5];
  const float* Wo   = (const float*)d_in[6];
  const float* W1   = (const float*)d_in[7];
  const float* b1   = (const float*)d_in[8];
  const float* W2   = (const float*)d_in[9];
  const float* b2   = (const float*)d_in[10];
  const float* g1   = (const float*)d_in[11];
  const float* g2   = (const float*)d_in[12];
  float* out = (float*)d_out;

  char* ws = (char*)d_ws;
  size_t off = 0;
  auto take = [&](size_t bytes) -> char* {
    char* p = ws + off;
    off = (off + bytes + 255) & ~(size_t)255;
    return p;
  };
  u16*  wqkv_t = (u16*) take((size_t)3072*1024*2);
  u16*  wo_t   = (u16*) take((size_t)1024*1024*2);
  u16*  w1_t   = (u16*) take((size_t)4096*1024*2);
  u16*  w2_t   = (u16*) take((size_t)1024*4096*2);
  u16*  hbuf   = (u16*) take((size_t)4096*1024*2);
  u16*  qkv    = (u16*) take((size_t)4096*3072*2);
  u16*  attn   = (u16*) take((size_t)4096*1024*2);
  float* x2    = (float*)take((size_t)4096*1024*4);
  u16*  h2     = (u16*) take((size_t)4096*1024*2);
  u16*  fbuf   = (u16*) take((size_t)4096*4096*2);
  unsigned char* nmask = (unsigned char*)take(BB*SSEQ);
  float* mpbuf = (float*)take((size_t)NSPLIT*NROWS*4);
  float* lpbuf = (float*)take((size_t)NSPLIT*NROWS*4);
  u16* Opart = fbuf;   // alias: consumed by attn_merge before FFN1 writes fbuf

  hipFuncSetAttribute(reinterpret_cast<const void*>(gemm8p<0>),
                      hipFuncAttributeMaxDynamicSharedMemorySize, 98304);
  hipFuncSetAttribute(reinterpret_cast<const void*>(gemm8p<2>),
                      hipFuncAttributeMaxDynamicSharedMemorySize, 98304);

  normalize_mask<<<1, 1024, 0, stream>>>(mask, nmask);

  dim3 tb(32, 8);
  transpose_to_bf16<<<dim3(32, 32),  tb, 0, stream>>>(Wq, wqkv_t,                      1024, 1024);
  transpose_to_bf16<<<dim3(32, 32),  tb, 0, stream>>>(Wk, wqkv_t + (size_t)1024*1024,  1024, 1024);
  transpose_to_bf16<<<dim3(32, 32),  tb, 0, stream>>>(Wv, wqkv_t + (size_t)2048*1024,  1024, 1024);
  transpose_to_bf16<<<dim3(32, 32),  tb, 0, stream>>>(Wo, wo_t,                        1024, 1024);
  transpose_to_bf16<<<dim3(128, 32), tb, 0, stream>>>(W1, w1_t,                        1024, 4096);
  transpose_to_bf16<<<dim3(32, 128), tb, 0, stream>>>(W2, w2_t,                        4096, 1024);

  rmsnorm_k<<<4096, 256, 0, stream>>>(x, g1, hbuf, DIMD);

  gemm8p<0><<<dim3(3072/256, 4096/256), 512, 98304, stream>>>(hbuf, wqkv_t, qkv, nullptr, 4096, 3072, 1024);

  attn_part<<<dim3(2*SSEQ/64, NHEAD, NSPLIT), 256, 0, stream>>>(qkv, bias, nmask, Opart, mpbuf, lpbuf);
  attn_merge<<<dim3(NROWS/16), 256, 0, stream>>>(Opart, mpbuf, lpbuf, attn);

  gemm_bt<1,128><<<dim3(1024/128, 4096/128), 256, 0, stream>>>(attn, wo_t, nullptr, x2, nullptr, x, 4096, 1024, 1024);

  rmsnorm_k<<<4096, 256, 0, stream>>>(x2, g2, h2, DIMD);

  gemm8p<2><<<dim3(4096/256, 4096/256), 512, 98304, stream>>>(h2, w1_t, fbuf, b1, 4096, 4096, 1024);

  gemm_bt<3,128><<<dim3(1024/128, 4096/128), 256, 0, stream>>>(fbuf, w2_t, nullptr, out, b2, x2, 4096, 1024, 4096);
}

// Round 7
// 426.062 us; speedup vs baseline: 1.0468x; 1.0468x over previous
//
#include <hip/hip_runtime.h>
#include <math.h>

typedef __attribute__((ext_vector_type(8))) short   short8;
typedef __attribute__((ext_vector_type(4))) short   short4v;
typedef __attribute__((ext_vector_type(8))) __bf16  bf16x8;
typedef __attribute__((ext_vector_type(4))) float   f32x4;
typedef unsigned short u16;

#define DIMD 1024
#define NHEAD 16
#define HD 64
#define FFD 4096
#define BB 2
#define SSEQ 2048
#define NSPLIT 4
#define KVSPAN (SSEQ / NSPLIT)
#define NROWS (BB * NHEAD * SSEQ)
#define NEGF -3.4028235e38f

__device__ __forceinline__ u16 f2bf(float f){
  unsigned u = __float_as_uint(f);
  u += 0x7FFFu + ((u >> 16) & 1u);
  return (u16)(u >> 16);
}
__device__ __forceinline__ float bf2f(u16 v){
  return __uint_as_float(((unsigned)v) << 16);
}
__device__ __forceinline__ void gload16(const u16* g, u16* l){
  __builtin_amdgcn_global_load_lds((const __attribute__((address_space(1))) void*)g,
                                   (__attribute__((address_space(3))) void*)l, 16, 0, 0);
}

// ---------------- mask dtype discriminator + normalizer ----------------
__global__ void normalize_mask(const unsigned char* __restrict__ m, unsigned char* __restrict__ outm){
  __shared__ int any;
  if (threadIdx.x == 0) any = 0;
  __syncthreads();
  int bad = 0;
  for (int i = threadIdx.x; i < BB * SSEQ; i += 1024)
    if ((i & 3) && m[i]) bad = 1;
  if (bad) atomicOr(&any, 1);
  __syncthreads();
  bool is_i32 = (any == 0);
  if (is_i32){
    const int* mi = (const int*)m;
    for (int k = threadIdx.x; k < BB * SSEQ; k += 1024)
      outm[k] = (unsigned char)(mi[k] != 0);
  } else {
    for (int k = threadIdx.x; k < BB * SSEQ; k += 1024)
      outm[k] = m[k] ? 1 : 0;
  }
}

// ---------------- weight transpose + fp32->bf16 ----------------
__global__ void transpose_to_bf16(const float* __restrict__ W, u16* __restrict__ Wt, int K, int N){
  __shared__ float tile[32][33];
  int n0 = blockIdx.x * 32, k0 = blockIdx.y * 32;
  int tx = threadIdx.x, ty = threadIdx.y;   // 32 x 8
  #pragma unroll
  for (int i = 0; i < 32; i += 8)
    tile[ty + i][tx] = W[(size_t)(k0 + ty + i) * N + n0 + tx];
  __syncthreads();
  #pragma unroll
  for (int i = 0; i < 32; i += 8)
    Wt[(size_t)(n0 + ty + i) * K + k0 + tx] = f2bf(tile[tx][ty + i]);
}

// ---------------- V global transpose: qkv V-block -> vt[b,h][dcol][S] ----------------
// grid (S/32, 2, B*H), block (32,8). Tile [32 s][32 d].
__global__ void vtrans(const u16* __restrict__ qkv, u16* __restrict__ vt){
  __shared__ u16 tile[32][33];
  int s0 = blockIdx.x * 32, d0 = blockIdx.y * 32;
  int bh = blockIdx.z;              // b*NHEAD + h
  int b = bh >> 4, h = bh & 15;
  int tx = threadIdx.x, ty = threadIdx.y;
  const u16* src = qkv + (size_t)(b * SSEQ) * 3072 + 2048 + h * HD + d0;
  #pragma unroll
  for (int i = 0; i < 32; i += 8)
    tile[ty + i][tx] = src[(size_t)(s0 + ty + i) * 3072 + tx];
  __syncthreads();
  u16* dst = vt + ((size_t)bh * HD + d0) * SSEQ + s0;
  #pragma unroll
  for (int i = 0; i < 32; i += 8)
    dst[(size_t)(ty + i) * SSEQ + tx] = tile[tx][ty + i];
}

// ---------------- RMSNorm: fp32 in -> bf16 out ----------------
__global__ __launch_bounds__(256) void rmsnorm_k(const float* __restrict__ x, const float* __restrict__ g,
                                                 u16* __restrict__ out, int D){
  int row = blockIdx.x;
  const float* xr = x + (size_t)row * D;
  float ss = 0.f;
  for (int i = threadIdx.x * 4; i < D; i += 1024){
    float4 v = *(const float4*)&xr[i];
    ss += v.x*v.x + v.y*v.y + v.z*v.z + v.w*v.w;
  }
  #pragma unroll
  for (int o = 32; o > 0; o >>= 1) ss += __shfl_down(ss, o);
  __shared__ float red[4];
  if ((threadIdx.x & 63) == 0) red[threadIdx.x >> 6] = ss;
  __syncthreads();
  float tot = red[0] + red[1] + red[2] + red[3];
  float rs = rsqrtf(tot / (float)D + 1e-6f);
  for (int i = threadIdx.x * 4; i < D; i += 1024){
    float4 v  = *(const float4*)&xr[i];
    float4 gv = *(const float4*)&g[i];
    ushort4 o4;
    o4.x = f2bf(v.x * rs * gv.x);
    o4.y = f2bf(v.y * rs * gv.y);
    o4.z = f2bf(v.z * rs * gv.z);
    o4.w = f2bf(v.w * rs * gv.w);
    *(ushort4*)&out[(size_t)row * D + i] = o4;
  }
}

// ================= 8-phase-style 256x256 GEMM, BK=32, 3-deep pipeline =================
template<int EPI>
__global__ __launch_bounds__(512, 2) void gemm8p(const u16* __restrict__ A, const u16* __restrict__ Bt,
                                                 u16* __restrict__ outb, const float* __restrict__ bias,
                                                 int M, int N, int K){
  extern __shared__ u16 lds[];   // 3 * 16384 u16
  const int tid = threadIdx.x;
  const int lane = tid & 63, lr = lane >> 4, lc = lane & 15;
  const int wid = tid >> 6, wr = wid >> 2, wc = wid & 3;
  const int m0 = blockIdx.y * 256, n0 = blockIdx.x * 256;
  const int NT = K >> 5;
  const int slot8 = ((lr ^ (lc & 3)) << 3);

  f32x4 acc[8][4];
  #pragma unroll
  for (int i = 0; i < 8; i++)
    #pragma unroll
    for (int j = 0; j < 4; j++) acc[i][j] = (f32x4){0.f,0.f,0.f,0.f};

  const int srow = tid >> 2;
  const int scg  = (tid & 3) ^ (srow & 3);

  auto stage = [&](int t, int buf, int rsel){
    int row = ((rsel & 1) << 7) + srow;
    const u16* src = ((rsel < 2) ? A + (size_t)(m0 + row) * K
                                 : Bt + (size_t)(n0 + row) * K) + t * 32 + scg * 8;
    u16* dst = lds + buf * 16384 + ((rsel & 2) << 12) + ((rsel & 1) << 12) + tid * 8;
    gload16(src, dst);
  };
  auto ldA = [&](int buf, int mi) -> bf16x8 {
    int ra = wr * 128 + mi * 16 + lc;
    return *(const bf16x8*)&lds[buf * 16384 + ra * 32 + slot8];
  };
  auto ldB = [&](int buf, int ni) -> bf16x8 {
    int rb = wc * 64 + ni * 16 + lc;
    return *(const bf16x8*)&lds[buf * 16384 + 8192 + rb * 32 + slot8];
  };

  #pragma unroll
  for (int rs = 0; rs < 4; rs++) stage(0, 0, rs);
  #pragma unroll
  for (int rs = 0; rs < 4; rs++) stage(1, 1, rs);
  asm volatile("s_waitcnt vmcnt(4)" ::: "memory");
  __builtin_amdgcn_s_barrier();

  int buf = 0;
  for (int t = 0; t < NT; t++){
    int sbuf = buf + 2; if (sbuf >= 3) sbuf -= 3;
    bool ds = (t + 2 < NT);
    bf16x8 a[4], b[4];
    #pragma unroll
    for (int mi = 0; mi < 4; mi++) a[mi] = ldA(buf, mi);
    #pragma unroll
    for (int ni = 0; ni < 4; ni++) b[ni] = ldB(buf, ni);
    if (ds){ stage(t + 2, sbuf, 0); stage(t + 2, sbuf, 1); }
    __builtin_amdgcn_s_barrier();
    __builtin_amdgcn_s_setprio(1);
    #pragma unroll
    for (int mi = 0; mi < 4; mi++)
      #pragma unroll
      for (int ni = 0; ni < 4; ni++)
        acc[mi][ni] = __builtin_amdgcn_mfma_f32_16x16x32_bf16(a[mi], b[ni], acc[mi][ni], 0, 0, 0);
    __builtin_amdgcn_s_setprio(0);
    __builtin_amdgcn_s_barrier();
    #pragma unroll
    for (int mi = 0; mi < 4; mi++) a[mi] = ldA(buf, mi + 4);
    if (ds){ stage(t + 2, sbuf, 2); stage(t + 2, sbuf, 3); }
    __builtin_amdgcn_s_barrier();
    __builtin_amdgcn_s_setprio(1);
    #pragma unroll
    for (int mi = 0; mi < 4; mi++)
      #pragma unroll
      for (int ni = 0; ni < 4; ni++)
        acc[mi + 4][ni] = __builtin_amdgcn_mfma_f32_16x16x32_bf16(a[mi], b[ni], acc[mi + 4][ni], 0, 0, 0);
    __builtin_amdgcn_s_setprio(0);
    if (t + 2 < NT)      { asm volatile("s_waitcnt vmcnt(4)" ::: "memory"); }
    else if (t + 1 < NT) { asm volatile("s_waitcnt vmcnt(0)" ::: "memory"); }
    __builtin_amdgcn_s_barrier();
    buf++; if (buf == 3) buf = 0;
  }

  #pragma unroll
  for (int mi = 0; mi < 8; mi++){
    #pragma unroll
    for (int ni = 0; ni < 4; ni++){
      int col = n0 + wc * 64 + ni * 16 + lc;
      #pragma unroll
      for (int r = 0; r < 4; r++){
        int row = m0 + wr * 128 + mi * 16 + lr * 4 + r;
        float v = acc[mi][ni][r];
        if (EPI == 2){
          v += bias[col];
          v = 0.5f * v * (1.f + erff(v * 0.70710678118654752f));
        }
        outb[(size_t)row * N + col] = f2bf(v);
      }
    }
  }
}

// ---------------- GEMM (m97 structure): O-proj / FFN2 ----------------
template<int EPI, int BN>
__global__ __launch_bounds__(256) void gemm_bt(const u16* __restrict__ A, const u16* __restrict__ Bt,
                                               u16* __restrict__ outb, float* __restrict__ outf,
                                               const float* __restrict__ bias, const float* __restrict__ resid,
                                               int M, int N, int K){
  constexpr int NI = BN / 32;
  __shared__ u16 As[128 * 64];
  __shared__ u16 Bs[BN * 64];
  const int tid = threadIdx.x;
  const int wid = tid >> 6, lane = tid & 63, lr = lane >> 4, lc = lane & 15;
  const int wr = wid >> 1, wc = wid & 1;
  const int m0 = blockIdx.y * 128, n0 = blockIdx.x * BN;

  f32x4 acc[4][NI];
  #pragma unroll
  for (int i = 0; i < 4; i++)
    #pragma unroll
    for (int j = 0; j < NI; j++) acc[i][j] = (f32x4){0.f,0.f,0.f,0.f};

  for (int k0 = 0; k0 < K; k0 += 64){
    __syncthreads();
    #pragma unroll
    for (int j = 0; j < 4; j++){
      int c = tid + 256 * j;
      gload16(A + (size_t)(m0 + (c >> 3)) * K + k0 + (c & 7) * 8, As + c * 8);
    }
    #pragma unroll
    for (int j = 0; j < NI; j++){
      int c = tid + 256 * j;
      gload16(Bt + (size_t)(n0 + (c >> 3)) * K + k0 + (c & 7) * 8, Bs + c * 8);
    }
    __syncthreads();
    #pragma unroll
    for (int kk = 0; kk < 2; kk++){
      bf16x8 a[4], b[NI];
      #pragma unroll
      for (int mi = 0; mi < 4; mi++) a[mi] = *(const bf16x8*)&As[(wr*64 + mi*16 + lc)*64 + kk*32 + lr*8];
      #pragma unroll
      for (int ni = 0; ni < NI; ni++) b[ni] = *(const bf16x8*)&Bs[(wc*(BN/2) + ni*16 + lc)*64 + kk*32 + lr*8];
      #pragma unroll
      for (int mi = 0; mi < 4; mi++)
        #pragma unroll
        for (int ni = 0; ni < NI; ni++)
          acc[mi][ni] = __builtin_amdgcn_mfma_f32_16x16x32_bf16(a[mi], b[ni], acc[mi][ni], 0, 0, 0);
    }
  }

  #pragma unroll
  for (int mi = 0; mi < 4; mi++){
    #pragma unroll
    for (int ni = 0; ni < NI; ni++){
      #pragma unroll
      for (int r = 0; r < 4; r++){
        int row = m0 + wr*64 + mi*16 + lr*4 + r;
        int col = n0 + wc*(BN/2) + ni*16 + lc;
        float v = acc[mi][ni][r];
        size_t idx = (size_t)row * N + col;
        if (EPI == 0){
          outb[idx] = f2bf(v);
        } else if (EPI == 1){
          outf[idx] = v + resid[idx];
        } else if (EPI == 2){
          v += bias[col];
          v = 0.5f * v * (1.f + erff(v * 0.70710678118654752f));
          outb[idx] = f2bf(v);
        } else {
          outf[idx] = v + bias[col] + resid[idx];
        }
      }
    }
  }
}

// ---------------- flash attention, split-KV partial (swapped QK^T, V^T pre-transposed) ----------------
// grid (2*S/64, H, NSPLIT): blockIdx.x = qblk*2 + b
__global__ __launch_bounds__(256) void attn_part(const u16* __restrict__ qkv, const u16* __restrict__ vt,
                                                 const float* __restrict__ bias,
                                                 const unsigned char* __restrict__ mask,
                                                 u16* __restrict__ Opart, float* __restrict__ mp, float* __restrict__ lp){
  __shared__ u16 Ks [64][72];
  __shared__ u16 VtB[64 * 64];       // [dcol][key], XOR-swizzled
  __shared__ u16 PsB [4 * 16 * 72];

  const int tid = threadIdx.x;
  const int wid = tid >> 6, lane = tid & 63, lr = lane >> 4, lc = lane & 15;
  const int b  = blockIdx.x & 1;
  const int q0 = (blockIdx.x >> 1) * 64;
  const int h  = blockIdx.y;
  const int sp = blockIdx.z;
  const int qrow = q0 + wid * 16;
  const int kv_lo = sp * KVSPAN, kv_hi = kv_lo + KVSPAN;

  char* vtl = (char*)VtB;
  u16*  psw = PsB + wid * 16 * 72;

  bf16x8 qf0, qf1;
  {
    const u16* qp = qkv + ((size_t)(b * SSEQ + qrow + lc)) * 3072 + h * HD;
    qf0 = *(const bf16x8*)(qp + lr * 8);
    qf1 = *(const bf16x8*)(qp + 32 + lr * 8);
  }

  // K staging: c in {tid, tid+256}: krow=c>>3, 8 cols at (c&7)*8 (of 64)
  const int c0 = tid, c1 = tid + 256;
  const u16* kbase = qkv + (size_t)b * SSEQ * 3072 + 1024 + h * HD;
  auto kaddr = [&](int kv0, int c){ return kbase + (size_t)(kv0 + (c >> 3)) * 3072 + (c & 7) * 8; };
  // V^T staging: dcol=c>>3, key8=(c&7)*8 from vt[bh][dcol][kv0+key8..]
  const u16* vbase = vt + (size_t)(b * NHEAD + h) * HD * SSEQ;
  auto vaddr = [&](int kv0, int c){ return vbase + (size_t)(c >> 3) * SSEQ + kv0 + (c & 7) * 8; };
  auto vst = [&](int c, short8 v){
    int byte = (c >> 3) * 128 + (c & 7) * 16;
    byte ^= ((c >> 3) & 7) << 4;
    *(short8*)(vtl + byte) = v;
  };
  auto vld = [&](int row, int colbase) -> bf16x8 {   // row=dcol, colbase in u16
    int byte = row * 128 + colbase * 2;
    byte ^= ((row & 7) << 4);
    return *(const bf16x8*)(vtl + byte);
  };

  // bias/mask vector loads: per lane q=lc row, keys ni*16+lr*4..+3
  const float* brow = bias + ((size_t)h * SSEQ + (qrow + lc)) * SSEQ;
  const unsigned char* mrow_p = mask + b * SSEQ;
  float4 bvA[4]; unsigned mkA[4];
  auto bload = [&](int kv0, float4* bv, unsigned* mk){
    #pragma unroll
    for (int ni = 0; ni < 4; ni++){
      int key = kv0 + ni * 16 + lr * 4;
      bv[ni] = *(const float4*)&brow[key];
      mk[ni] = *(const unsigned*)&mrow_p[key];
    }
  };

  // prologue
  short8 kr0 = *(const short8*)kaddr(kv_lo, c0);
  short8 vr0 = *(const short8*)vaddr(kv_lo, c0);
  short8 kr1 = *(const short8*)kaddr(kv_lo, c1);
  short8 vr1 = *(const short8*)vaddr(kv_lo, c1);
  bload(kv_lo, bvA, mkA);

  float mrow = NEGF, lsum = 0.f;   // per lane: q = qrow + lc
  f32x4 oacc[4];
  #pragma unroll
  for (int d = 0; d < 4; d++) oacc[d] = (f32x4){0.f,0.f,0.f,0.f};

  for (int kv0 = kv_lo; kv0 < kv_hi; kv0 += 64){
    __syncthreads();
    *(short8*)&Ks[c0 >> 3][(c0 & 7) * 8] = kr0;
    *(short8*)&Ks[c1 >> 3][(c1 & 7) * 8] = kr1;
    vst(c0, vr0);
    vst(c1, vr1);
    __syncthreads();

    // prefetch next tile (hides under compute)
    int nxt = (kv0 + 64 < kv_hi) ? kv0 + 64 : kv_lo;
    kr0 = *(const short8*)kaddr(nxt, c0);
    vr0 = *(const short8*)vaddr(nxt, c0);
    kr1 = *(const short8*)kaddr(nxt, c1);
    vr1 = *(const short8*)vaddr(nxt, c1);
    float4 bvB[4]; unsigned mkB[4];
    bload(nxt, bvB, mkB);

    // ---- QK^T swapped: sf[ni][r] = S[key=kv0+ni*16+lr*4+r][q=qrow+lc] ----
    f32x4 sf[4];
    #pragma unroll
    for (int ni = 0; ni < 4; ni++) sf[ni] = (f32x4){0.f,0.f,0.f,0.f};
    __builtin_amdgcn_s_setprio(1);
    #pragma unroll
    for (int ni = 0; ni < 4; ni++){
      bf16x8 kf0 = *(const bf16x8*)&Ks[ni*16 + lc][lr*8];
      bf16x8 kf1 = *(const bf16x8*)&Ks[ni*16 + lc][32 + lr*8];
      sf[ni] = __builtin_amdgcn_mfma_f32_16x16x32_bf16(kf0, qf0, sf[ni], 0, 0, 0);
      sf[ni] = __builtin_amdgcn_mfma_f32_16x16x32_bf16(kf1, qf1, sf[ni], 0, 0, 0);
    }
    __builtin_amdgcn_s_setprio(0);

    // ---- scores + in-register row max ----
    float s[4][4];
    float tm = NEGF;
    #pragma unroll
    for (int ni = 0; ni < 4; ni++){
      #pragma unroll
      for (int r = 0; r < 4; r++){
        bool mk = ((mkA[ni] >> (8 * r)) & 0xffu) != 0;
        float v = sf[ni][r] * 0.125f + ((const float*)&bvA[ni])[r];
        v = mk ? NEGF : v;
        s[ni][r] = v;
        tm = fmaxf(tm, v);
      }
    }
    tm = fmaxf(tm, __shfl_xor(tm, 16));
    tm = fmaxf(tm, __shfl_xor(tm, 32));

    // ---- defer-max rescale ----
    if (__any(tm > mrow + 5.f)){
      float mnew = fmaxf(mrow, tm);
      float corr = __expf(mrow - mnew);
      lsum *= corr;
      mrow = mnew;
      float cr[4];
      #pragma unroll
      for (int r = 0; r < 4; r++) cr[r] = __shfl(corr, lr * 4 + r);
      #pragma unroll
      for (int d = 0; d < 4; d++)
        #pragma unroll
        for (int r = 0; r < 4; r++) oacc[d][r] *= cr[r];
    }

    // ---- P = exp(s-m), packed b64 store, in-register sum ----
    float psum = 0.f;
    #pragma unroll
    for (int ni = 0; ni < 4; ni++){
      short4v pk;
      #pragma unroll
      for (int r = 0; r < 4; r++){
        float sv = s[ni][r];
        float p = (sv < -1e30f) ? 0.f : __expf(sv - mrow);
        psum += p;
        pk[r] = (short)(__float_as_uint(p) >> 16);
      }
      *(short4v*)&psw[lc * 72 + ni * 16 + lr * 4] = pk;
    }
    psum += __shfl_xor(psum, 16);
    psum += __shfl_xor(psum, 32);
    lsum += psum;

    // ---- PV ----
    __builtin_amdgcn_s_setprio(1);
    #pragma unroll
    for (int kk = 0; kk < 2; kk++){
      bf16x8 pf = *(const bf16x8*)&psw[lc * 72 + kk * 32 + lr * 8];
      #pragma unroll
      for (int d = 0; d < 4; d++){
        bf16x8 vf = vld(d*16 + lc, kk*32 + lr*8);
        oacc[d] = __builtin_amdgcn_mfma_f32_16x16x32_bf16(pf, vf, oacc[d], 0, 0, 0);
      }
    }
    __builtin_amdgcn_s_setprio(0);

    #pragma unroll
    for (int ni = 0; ni < 4; ni++){ bvA[ni] = bvB[ni]; mkA[ni] = mkB[ni]; }
  }

  if (lane < 16){
    int ridx0 = (b * NHEAD + h) * SSEQ + qrow + lc;
    mp[sp * NROWS + ridx0] = mrow;
    lp[sp * NROWS + ridx0] = lsum;
  }
  #pragma unroll
  for (int r = 0; r < 4; r++){
    int ridx = (b * NHEAD + h) * SSEQ + qrow + lr*4 + r;
    #pragma unroll
    for (int d = 0; d < 4; d++)
      Opart[((size_t)(sp * NROWS + ridx)) * HD + d*16 + lc] = f2bf(oacc[d][r]);
  }
}

// ---------------- split-KV merge ----------------
__global__ __launch_bounds__(256) void attn_merge(const u16* __restrict__ Opart, const float* __restrict__ mp,
                                                  const float* __restrict__ lp, u16* __restrict__ attn){
  int row = blockIdx.x * 16 + (threadIdx.x >> 4);
  int tx = threadIdx.x & 15;
  float ms[NSPLIT], ls[NSPLIT];
  float m = NEGF;
  #pragma unroll
  for (int sp = 0; sp < NSPLIT; sp++){
    ms[sp] = mp[sp * NROWS + row];
    ls[sp] = lp[sp * NROWS + row];
    if (ls[sp] > 0.f) m = fmaxf(m, ms[sp]);
  }
  float acc0 = 0.f, acc1 = 0.f, acc2 = 0.f, acc3 = 0.f, ltot = 0.f;
  #pragma unroll
  for (int sp = 0; sp < NSPLIT; sp++){
    float e = (ls[sp] > 0.f) ? __expf(ms[sp] - m) : 0.f;
    ltot += ls[sp] * e;
    ushort4 o4 = *(const ushort4*)&Opart[((size_t)(sp * NROWS + row)) * HD + tx*4];
    acc0 += e * bf2f(o4.x);
    acc1 += e * bf2f(o4.y);
    acc2 += e * bf2f(o4.z);
    acc3 += e * bf2f(o4.w);
  }
  float inv = ltot > 0.f ? 1.f / ltot : 0.f;
  int b = row >> 15, h = (row >> 11) & 15, q = row & 2047;
  ushort4 r4;
  r4.x = f2bf(acc0 * inv);
  r4.y = f2bf(acc1 * inv);
  r4.z = f2bf(acc2 * inv);
  r4.w = f2bf(acc3 * inv);
  *(ushort4*)&attn[((size_t)(b * SSEQ + q)) * DIMD + h * HD + tx*4] = r4;
}

// ---------------- launch ----------------
extern "C" void kernel_launch(void* const* d_in, const int* in_sizes, int n_in,
                              void* d_out, int out_size, void* d_ws, size_t ws_size,
                              hipStream_t stream){
  const float* x    = (const float*)d_in[0];
  const unsigned char* mask = (const unsigned char*)d_in[1];
  const float* bias = (const float*)d_in[2];
  const float* Wq   = (const float*)d_in[3];
  const float* Wk   = (const float*)d_in[4];
  const float* Wv   = (const float*)d_in[5];
  const float* Wo   = (const float*)d_in[6];
  const float* W1   = (const float*)d_in[7];
  const float* b1   = (const float*)d_in[8];
  const float* W2   = (const float*)d_in[9];
  const float* b2   = (const float*)d_in[10];
  const float* g1   = (const float*)d_in[11];
  const float* g2   = (const float*)d_in[12];
  float* out = (float*)d_out;

  char* ws = (char*)d_ws;
  size_t off = 0;
  auto take = [&](size_t bytes) -> char* {
    char* p = ws + off;
    off = (off + bytes + 255) & ~(size_t)255;
    return p;
  };
  u16*  wqkv_t = (u16*) take((size_t)3072*1024*2);
  u16*  wo_t   = (u16*) take((size_t)1024*1024*2);
  u16*  w1_t   = (u16*) take((size_t)4096*1024*2);
  u16*  w2_t   = (u16*) take((size_t)1024*4096*2);
  u16*  hbuf   = (u16*) take((size_t)4096*1024*2);
  u16*  qkv    = (u16*) take((size_t)4096*3072*2);
  u16*  attn   = (u16*) take((size_t)4096*1024*2);
  float* x2    = (float*)take((size_t)4096*1024*4);
  u16*  h2     = (u16*) take((size_t)4096*1024*2);
  u16*  fbuf   = (u16*) take((size_t)4096*4096*2);
  unsigned char* nmask = (unsigned char*)take(BB*SSEQ);
  float* mpbuf = (float*)take((size_t)NSPLIT*NROWS*4);
  float* lpbuf = (float*)take((size_t)NSPLIT*NROWS*4);
  u16* Opart = fbuf;   // alias: consumed by attn_merge before FFN1 writes fbuf
  u16* vt_g  = hbuf;   // alias: hbuf (rmsnorm output) is dead after QKV GEMM; exactly 8.4 MB

  hipFuncSetAttribute(reinterpret_cast<const void*>(gemm8p<0>),
                      hipFuncAttributeMaxDynamicSharedMemorySize, 98304);
  hipFuncSetAttribute(reinterpret_cast<const void*>(gemm8p<2>),
                      hipFuncAttributeMaxDynamicSharedMemorySize, 98304);

  normalize_mask<<<1, 1024, 0, stream>>>(mask, nmask);

  dim3 tb(32, 8);
  transpose_to_bf16<<<dim3(32, 32),  tb, 0, stream>>>(Wq, wqkv_t,                      1024, 1024);
  transpose_to_bf16<<<dim3(32, 32),  tb, 0, stream>>>(Wk, wqkv_t + (size_t)1024*1024,  1024, 1024);
  transpose_to_bf16<<<dim3(32, 32),  tb, 0, stream>>>(Wv, wqkv_t + (size_t)2048*1024,  1024, 1024);
  transpose_to_bf16<<<dim3(32, 32),  tb, 0, stream>>>(Wo, wo_t,                        1024, 1024);
  transpose_to_bf16<<<dim3(128, 32), tb, 0, stream>>>(W1, w1_t,                        1024, 4096);
  transpose_to_bf16<<<dim3(32, 128), tb, 0, stream>>>(W2, w2_t,                        4096, 1024);

  rmsnorm_k<<<4096, 256, 0, stream>>>(x, g1, hbuf, DIMD);

  gemm8p<0><<<dim3(3072/256, 4096/256), 512, 98304, stream>>>(hbuf, wqkv_t, qkv, nullptr, 4096, 3072, 1024);

  vtrans<<<dim3(SSEQ/32, 2, BB*NHEAD), tb, 0, stream>>>(qkv, vt_g);

  attn_part<<<dim3(2*SSEQ/64, NHEAD, NSPLIT), 256, 0, stream>>>(qkv, vt_g, bias, nmask, Opart, mpbuf, lpbuf);
  attn_merge<<<dim3(NROWS/16), 256, 0, stream>>>(Opart, mpbuf, lpbuf, attn);

  gemm_bt<1,64><<<dim3(1024/64, 4096/128), 256, 0, stream>>>(attn, wo_t, nullptr, x2, nullptr, x, 4096, 1024, 1024);

  rmsnorm_k<<<4096, 256, 0, stream>>>(x2, g2, h2, DIMD);

  gemm8p<2><<<dim3(4096/256, 4096/256), 512, 98304, stream>>>(h2, w1_t, fbuf, b1, 4096, 4096, 1024);

  gemm_bt<3,64><<<dim3(1024/64, 4096/128), 256, 0, stream>>>(fbuf, w2_t, nullptr, out, b2, x2, 4096, 1024, 4096);
}